// Round 7
// baseline (1254.265 us; speedup 1.0000x reference)
//
#include <hip/hip_runtime.h>
#include <math.h>

// Problem constants
// B=256, T=512, E=768, Hd=50, 4*Hd=200, H=100, K=11, START=9, STOP=10, NEG=-1000
// M = B*T = 131072

typedef _Float16 half8 __attribute__((ext_vector_type(8)));
typedef _Float16 half4 __attribute__((ext_vector_type(4)));
typedef float f32x4 __attribute__((ext_vector_type(4)));
typedef float f32x2 __attribute__((ext_vector_type(2)));

// ---------------------------------------------------------------------------
// Kernel 1: xw[M][400] = emb[M][768] @ concat(W_ih_f, W_ih_b)^T
// Split-precision fp16 MFMA (hi+lo, 3 products) => ~fp32 accuracy at f16 rate.
// ---------------------------------------------------------------------------
__global__ __launch_bounds__(256) void k_gemm_split(
    const float* __restrict__ emb,
    const float* __restrict__ Wf,     // [200][768]
    const float* __restrict__ Wb,     // [200][768]
    float* __restrict__ xw)           // [M][400]
{
    __shared__ _Float16 Ah[128 * 64];
    __shared__ _Float16 Al[128 * 64];
    __shared__ _Float16 Bh[80 * 64];
    __shared__ _Float16 Bl[80 * 64];

    const int bid = blockIdx.x;
    const int wg  = (bid & 7) * 640 + (bid >> 3);
    const int mt  = wg / 5;
    const int nb  = wg - mt * 5;
    const size_t m0 = (size_t)mt * 128;
    const int n0 = nb * 80;

    const int tid  = threadIdx.x;
    const int lane = tid & 63;
    const int w    = tid >> 6;        // wave 0..3, rows w*32..+31
    const int grp  = lane >> 4;       // 0..3
    const int r16  = lane & 15;

    f32x4 acc[2][5];
    #pragma unroll
    for (int m = 0; m < 2; ++m)
        #pragma unroll
        for (int n = 0; n < 5; ++n) acc[m][n] = (f32x4){0.f, 0.f, 0.f, 0.f};

    for (int kt = 0; kt < 12; ++kt) {
        const int k0 = kt * 64;
        __syncthreads();

        #pragma unroll
        for (int j = 0; j < 8; ++j) {
            const int flat = j * 256 + tid;      // 0..2047 float4 slots
            const int row  = flat >> 4;          // 0..127
            const int q    = flat & 15;          // float4 col
            const float4 v = *(const float4*)(emb + (m0 + row) * 768 + k0 + q * 4);
            half4 hv, lv;
            hv[0] = (_Float16)v.x; lv[0] = (_Float16)(v.x - (float)hv[0]);
            hv[1] = (_Float16)v.y; lv[1] = (_Float16)(v.y - (float)hv[1]);
            hv[2] = (_Float16)v.z; lv[2] = (_Float16)(v.z - (float)hv[2]);
            hv[3] = (_Float16)v.w; lv[3] = (_Float16)(v.w - (float)hv[3]);
            const int s    = (q >> 1) ^ (row & 7);
            const int addr = row * 64 + s * 8 + (q & 1) * 4;
            *(half4*)(Ah + addr) = hv;
            *(half4*)(Al + addr) = lv;
        }
        #pragma unroll
        for (int j = 0; j < 5; ++j) {
            const int flat = j * 256 + tid;      // 0..1279
            const int row  = flat >> 4;          // 0..79
            const int q    = flat & 15;
            const int n    = n0 + row;
            const float* src = (n < 200) ? (Wf + (size_t)n * 768)
                                         : (Wb + (size_t)(n - 200) * 768);
            const float4 v = *(const float4*)(src + k0 + q * 4);
            half4 hv, lv;
            hv[0] = (_Float16)v.x; lv[0] = (_Float16)(v.x - (float)hv[0]);
            hv[1] = (_Float16)v.y; lv[1] = (_Float16)(v.y - (float)hv[1]);
            hv[2] = (_Float16)v.z; lv[2] = (_Float16)(v.z - (float)hv[2]);
            hv[3] = (_Float16)v.w; lv[3] = (_Float16)(v.w - (float)hv[3]);
            const int s    = (q >> 1) ^ (row & 7);
            const int addr = row * 64 + s * 8 + (q & 1) * 4;
            *(half4*)(Bh + addr) = hv;
            *(half4*)(Bl + addr) = lv;
        }
        __syncthreads();

        #pragma unroll
        for (int ks = 0; ks < 2; ++ks) {
            const int kslot = ks * 4 + grp;
            half8 ah[2], al[2], bh[5], bl[5];
            #pragma unroll
            for (int m = 0; m < 2; ++m) {
                const int row = w * 32 + m * 16 + r16;
                const int ad  = row * 64 + (kslot ^ (row & 7)) * 8;
                ah[m] = *(half8*)(Ah + ad);
                al[m] = *(half8*)(Al + ad);
            }
            #pragma unroll
            for (int n = 0; n < 5; ++n) {
                const int row = n * 16 + r16;
                const int ad  = row * 64 + (kslot ^ (row & 7)) * 8;
                bh[n] = *(half8*)(Bh + ad);
                bl[n] = *(half8*)(Bl + ad);
            }
            #pragma unroll
            for (int m = 0; m < 2; ++m)
                #pragma unroll
                for (int n = 0; n < 5; ++n) {
                    acc[m][n] = __builtin_amdgcn_mfma_f32_16x16x32_f16(ah[m], bh[n], acc[m][n], 0, 0, 0);
                    acc[m][n] = __builtin_amdgcn_mfma_f32_16x16x32_f16(ah[m], bl[n], acc[m][n], 0, 0, 0);
                    acc[m][n] = __builtin_amdgcn_mfma_f32_16x16x32_f16(al[m], bh[n], acc[m][n], 0, 0, 0);
                }
        }
    }

    #pragma unroll
    for (int m = 0; m < 2; ++m) {
        #pragma unroll
        for (int n = 0; n < 5; ++n) {
            #pragma unroll
            for (int i = 0; i < 4; ++i) {
                const size_t row = m0 + w * 32 + m * 16 + (lane >> 4) * 4 + i;
                const int    col = n0 + n * 16 + (lane & 15);
                xw[row * 400 + col] = acc[m][n][i];
            }
        }
    }
}

// ---------------------------------------------------------------------------
// Kernel 2: bidirectional LSTM recurrence. One block per (batch, dir).
// WEIGHTS LIVE IN LDS, transposed+vectorized: WT4[q][tid][e] = Whh[grow(tid)][4q+e]
// -> thread tid reads its 4 weights per q as ONE conflict-free ds_read_b128
// (lane-consecutive 16B, immediate offsets q*4096B). Removes the per-step
// 200B/thread L2/scratch weight re-fetch that regalloc forced in R1-R6
// (VGPR_Count pinned at 40 regardless of hints). FMA order bit-identical
// to the passing version.
// ---------------------------------------------------------------------------
__global__ __launch_bounds__(256, 1) void k_lstm(
    const float* __restrict__ xw,     // [131072][400] (fwd gates 0..199, bwd 200..399)
    const float* __restrict__ Whh_f,  // [200][50]
    const float* __restrict__ Whh_b,
    const float* __restrict__ bf_,    // [200]
    const float* __restrict__ bb_,
    float* __restrict__ hout)         // [131072][100] (fwd 0..49, bwd 50..99)
{
    const int b   = blockIdx.x >> 1;
    const int dir = blockIdx.x & 1;
    const int tid = threadIdx.x;
    const int wv  = tid >> 6;         // wave 0..3
    const int lane = tid & 63;
    const int g4  = lane >> 4;        // gate 0..3 (i,f,g,o)
    const int r16 = lane & 15;
    const int u   = wv * 16 + r16;    // hidden unit 0..63 (active < 50)
    const bool act = (u < 50);
    const int grow = g4 * 50 + u;     // gate row 0..199 (when act)

    __shared__ __align__(16) float WT4[13][256][4];   // 53248 B, weights
    __shared__ __align__(16) float hb[2][52];

    const float* Whh  = dir ? Whh_b : Whh_f;
    const float* bias = dir ? bb_ : bf_;

    // zero-fill (pads + inactive-thread slots), then transposed fill
    for (int i = tid; i < 13 * 256 * 4; i += 256) ((float*)WT4)[i] = 0.f;
    __syncthreads();
    for (int s = tid; s < 10000; s += 256) {
        const int row = s / 50;                 // gate row 0..199
        const int k   = s - row * 50;           // 0..49
        const int uu  = row % 50;
        const int gg  = row / 50;
        const int dst = (uu >> 4) * 64 + gg * 16 + (uu & 15);   // reading tid
        WT4[k >> 2][dst][k & 3] = Whh[s];
    }
    if (tid < 104) ((float*)hb)[tid] = 0.f;
    const float bg = act ? bias[grow] : 0.f;
    float c = 0.f;
    __syncthreads();

    const size_t base = (size_t)b * 512;
    const int col = dir * 200 + grow;
    const float* wbase = &WT4[0][tid][0];       // q-stride = 1024 floats (4096 B)

    float xv[4];
    #pragma unroll
    for (int k = 0; k < 4; ++k) {
        const int tt = dir ? (511 - k) : k;
        xv[k] = act ? xw[(base + tt) * 400 + col] : 0.f;
    }

    int cur = 0;
    for (int it0 = 0; it0 < 512; it0 += 4) {
        #pragma unroll
        for (int k = 0; k < 4; ++k) {
            const int it = it0 + k;
            const int t  = dir ? (511 - it) : it;
            const float xcur = xv[k];
            if (it + 4 < 512) {
                const int tn = dir ? (511 - (it + 4)) : (it + 4);
                if (act) xv[k] = xw[(base + tn) * 400 + col];
            }

            const f32x4* h4 = (const f32x4*)(&hb[cur][0]);
            float s0 = bg + xcur, s1 = 0.f, s2 = 0.f, s3 = 0.f;
            #pragma unroll
            for (int q = 0; q < 13; ++q) {
                const f32x4 wq = *(const f32x4*)(wbase + q * 1024);
                const f32x4 hv = h4[q];
                s0 = fmaf(wq[0], hv[0], s0);
                s1 = fmaf(wq[1], hv[1], s1);
                s2 = fmaf(wq[2], hv[2], s2);
                s3 = fmaf(wq[3], hv[3], s3);
            }
            const float sum = (s0 + s1) + (s2 + s3);

            const float gi = __shfl(sum, r16);
            const float gf = __shfl(sum, r16 + 16);
            const float gg = __shfl(sum, r16 + 32);
            const float go = __shfl(sum, r16 + 48);

            if (g4 == 0 && act) {
                const float si = __builtin_amdgcn_rcpf(1.f + __expf(-gi));
                const float sf = __builtin_amdgcn_rcpf(1.f + __expf(-gf));
                const float tg = 1.f - 2.f * __builtin_amdgcn_rcpf(__expf(2.f * gg) + 1.f);
                c = sf * c + si * tg;
                const float th = 1.f - 2.f * __builtin_amdgcn_rcpf(__expf(2.f * c) + 1.f);
                const float so = __builtin_amdgcn_rcpf(1.f + __expf(-go));
                const float h = so * th;
                hout[(base + t) * 100 + dir * 50 + u] = h;
                hb[cur ^ 1][u] = h;
            }
            // LDS-visibility-only barrier: do NOT drain vmcnt (keeps hout
            // stores and the xw prefetch ring in flight across steps).
            asm volatile("s_waitcnt lgkmcnt(0)\n\ts_barrier" ::: "memory");
            cur ^= 1;
        }
    }
}

// ---------------------------------------------------------------------------
// Kernel 3: emissions logits[bt][11] = hout[bt][100] @ Wout^T + bout
// ---------------------------------------------------------------------------
__global__ __launch_bounds__(256) void k_emis(
    const float* __restrict__ hout,   // [131072][100]
    const float* __restrict__ Wout,   // [11][100]
    const float* __restrict__ bout,   // [11]
    float* __restrict__ logits)       // [131072][11]
{
    __shared__ float Wl[1104];
    __shared__ float bl[11];
    const int tid = threadIdx.x;
    for (int i = tid; i < 1100; i += 256) Wl[i] = Wout[i];
    if (tid < 11) bl[tid] = bout[tid];
    __syncthreads();

    const size_t bt = (size_t)blockIdx.x * 256 + tid;
    const float4* h4 = (const float4*)(hout + bt * 100);
    float acc[11];
    #pragma unroll
    for (int k = 0; k < 11; ++k) acc[k] = bl[k];
    #pragma unroll
    for (int q = 0; q < 25; ++q) {
        float4 v = h4[q];
        #pragma unroll
        for (int k = 0; k < 11; ++k) {
            const float4 wv = *(const float4*)&Wl[k * 100 + q * 4];
            acc[k] = fmaf(v.x, wv.x, fmaf(v.y, wv.y, fmaf(v.z, wv.z, fmaf(v.w, wv.w, acc[k]))));
        }
    }
    #pragma unroll
    for (int k = 0; k < 11; ++k) logits[bt * 11 + k] = acc[k];
}

// ---------------------------------------------------------------------------
// Kernel 4: CRF forward scan + logsumexp score + fused Viterbi backtrace.
// ONE wave per batch element, no barriers. Alpha in registers (shfl
// broadcast); transition column pinned as named VGPRs. libm expf/logf
// retained: paths require exact argmax agreement.
// ---------------------------------------------------------------------------
__global__ __launch_bounds__(64, 1) void k_crf(
    const float* __restrict__ logits,   // [131072][11]
    const int* __restrict__ mask,       // [256][512]
    const float* __restrict__ trans,    // [11][11]
    float* __restrict__ scores,         // [256]
    float* __restrict__ paths)          // [256][512] (as float)
{
    const int b = blockIdx.x;
    const int lane = threadIdx.x;
    const int lanec = (lane < 11) ? lane : 10;   // clamp for safe addressing

    __shared__ unsigned char bp[512][12];

    #define LDT(p) float tc##p = trans[(p) * 11 + lanec]
    LDT(0); LDT(1); LDT(2); LDT(3); LDT(4); LDT(5); LDT(6); LDT(7); LDT(8);
    LDT(9); LDT(10);
    #undef LDT
    asm volatile("" :
        "+v"(tc0), "+v"(tc1), "+v"(tc2), "+v"(tc3), "+v"(tc4), "+v"(tc5),
        "+v"(tc6), "+v"(tc7), "+v"(tc8), "+v"(tc9), "+v"(tc10));

    float myal = (lane == 9) ? 0.f : -1000.f;    // alpha[lane], lanes 0..10 live

    const size_t lbase = (size_t)b * 512;

    float f_cur = logits[lbase * 11 + lanec];
    int   m_cur = mask[lbase];

    for (int t = 0; t < 512; ++t) {
        float f_next = 0.f; int m_next = 1;
        if (t + 1 < 512) {
            f_next = logits[(lbase + t + 1) * 11 + lanec];
            m_next = mask[lbase + t + 1];
        }

        float v[11];
        float vmax = -1e30f; int amax = 0;
        #define CRFP(p) { const float alp = __shfl(myal, p);                 \
            const float vv = (alp + f_cur) + tc##p; v[p] = vv;               \
            if (vv > vmax) { vmax = vv; amax = p; } }
        CRFP(0) CRFP(1) CRFP(2) CRFP(3) CRFP(4) CRFP(5) CRFP(6) CRFP(7)
        CRFP(8) CRFP(9) CRFP(10)
        #undef CRFP

        float s = 0.f;
        #pragma unroll
        for (int p = 0; p < 11; ++p) s += expf(v[p] - vmax);
        const float na = vmax + logf(s);

        if (lane < 11) {
            if (m_cur > 0) {
                myal = na;
                bp[t][lane] = (unsigned char)amax;
            } else {
                bp[t][lane] = (unsigned char)lane;
            }
        }
        f_cur = f_next;
        m_cur = m_next;
    }

    // final scores + argmax (STOP = 10)
    float fin = (lane < 11) ? (myal + trans[lane * 11 + 10]) : -1e30f;
    float m = fin;
    int am = (lane < 11) ? lane : 1000;
    #pragma unroll
    for (int off = 8; off >= 1; off >>= 1) {
        float om = __shfl_xor(m, off, 16);
        int   oa = __shfl_xor(am, off, 16);
        if (om > m || (om == m && oa < am)) { m = om; am = oa; }
    }
    float s = (lane < 11) ? expf(fin - m) : 0.f;
    #pragma unroll
    for (int off = 8; off >= 1; off >>= 1) s += __shfl_xor(s, off, 16);

    if (lane == 0) {
        scores[b] = m + logf(s);
        int cur = am;
        paths[lbase + 511] = (float)cur;
        for (int t = 511; t >= 1; --t) {
            cur = bp[t][cur];
            paths[lbase + t - 1] = (float)cur;
        }
    }
}

// ---------------------------------------------------------------------------
extern "C" void kernel_launch(void* const* d_in, const int* in_sizes, int n_in,
                              void* d_out, int out_size, void* d_ws, size_t ws_size,
                              hipStream_t stream) {
    const float* emb   = (const float*)d_in[0];
    const int*   imask = (const int*)d_in[1];
    const float* Wihf  = (const float*)d_in[2];
    const float* Whhf  = (const float*)d_in[3];
    const float* bf_   = (const float*)d_in[4];
    const float* Wihb  = (const float*)d_in[5];
    const float* Whhb  = (const float*)d_in[6];
    const float* bb_   = (const float*)d_in[7];
    const float* Wout  = (const float*)d_in[8];
    const float* bout  = (const float*)d_in[9];
    const float* trans = (const float*)d_in[10];

    float* out = (float*)d_out;
    float* ws  = (float*)d_ws;
    float* xw     = ws;                          // 131072*400 f32 = 209.7 MB
    float* hout   = xw + (size_t)131072 * 400;   // 131072*100 f32 = 52.4 MB
    float* logits = hout + (size_t)131072 * 100; // 131072*11  f32 = 5.8 MB

    k_gemm_split<<<5120, 256, 0, stream>>>(emb, Wihf, Wihb, xw);
    k_lstm<<<512, 256, 0, stream>>>(xw, Whhf, Whhb, bf_, bb_, hout);
    k_emis<<<512, 256, 0, stream>>>(hout, Wout, bout, logits);
    k_crf<<<256, 64, 0, stream>>>(logits, imask, trans, out, out + 256);
}

// Round 8
// 1083.203 us; speedup vs baseline: 1.1579x; 1.1579x over previous
//
#include <hip/hip_runtime.h>
#include <math.h>

// Problem constants
// B=256, T=512, E=768, Hd=50, 4*Hd=200, H=100, K=11, START=9, STOP=10, NEG=-1000
// M = B*T = 131072

typedef _Float16 half8 __attribute__((ext_vector_type(8)));
typedef _Float16 half4 __attribute__((ext_vector_type(4)));
typedef float f32x4 __attribute__((ext_vector_type(4)));

// ---------------------------------------------------------------------------
// Kernel 1: xw[M][400] = emb[M][768] @ concat(W_ih_f, W_ih_b)^T
// Split-precision fp16 MFMA (hi+lo, 3 products) => ~fp32 accuracy at f16 rate.
// ---------------------------------------------------------------------------
__global__ __launch_bounds__(256) void k_gemm_split(
    const float* __restrict__ emb,
    const float* __restrict__ Wf,     // [200][768]
    const float* __restrict__ Wb,     // [200][768]
    float* __restrict__ xw)           // [M][400]
{
    __shared__ _Float16 Ah[128 * 64];
    __shared__ _Float16 Al[128 * 64];
    __shared__ _Float16 Bh[80 * 64];
    __shared__ _Float16 Bl[80 * 64];

    const int bid = blockIdx.x;
    const int wg  = (bid & 7) * 640 + (bid >> 3);
    const int mt  = wg / 5;
    const int nb  = wg - mt * 5;
    const size_t m0 = (size_t)mt * 128;
    const int n0 = nb * 80;

    const int tid  = threadIdx.x;
    const int lane = tid & 63;
    const int w    = tid >> 6;        // wave 0..3, rows w*32..+31
    const int grp  = lane >> 4;       // 0..3
    const int r16  = lane & 15;

    f32x4 acc[2][5];
    #pragma unroll
    for (int m = 0; m < 2; ++m)
        #pragma unroll
        for (int n = 0; n < 5; ++n) acc[m][n] = (f32x4){0.f, 0.f, 0.f, 0.f};

    for (int kt = 0; kt < 12; ++kt) {
        const int k0 = kt * 64;
        __syncthreads();

        #pragma unroll
        for (int j = 0; j < 8; ++j) {
            const int flat = j * 256 + tid;      // 0..2047 float4 slots
            const int row  = flat >> 4;          // 0..127
            const int q    = flat & 15;          // float4 col
            const float4 v = *(const float4*)(emb + (m0 + row) * 768 + k0 + q * 4);
            half4 hv, lv;
            hv[0] = (_Float16)v.x; lv[0] = (_Float16)(v.x - (float)hv[0]);
            hv[1] = (_Float16)v.y; lv[1] = (_Float16)(v.y - (float)hv[1]);
            hv[2] = (_Float16)v.z; lv[2] = (_Float16)(v.z - (float)hv[2]);
            hv[3] = (_Float16)v.w; lv[3] = (_Float16)(v.w - (float)hv[3]);
            const int s    = (q >> 1) ^ (row & 7);
            const int addr = row * 64 + s * 8 + (q & 1) * 4;
            *(half4*)(Ah + addr) = hv;
            *(half4*)(Al + addr) = lv;
        }
        #pragma unroll
        for (int j = 0; j < 5; ++j) {
            const int flat = j * 256 + tid;      // 0..1279
            const int row  = flat >> 4;          // 0..79
            const int q    = flat & 15;
            const int n    = n0 + row;
            const float* src = (n < 200) ? (Wf + (size_t)n * 768)
                                         : (Wb + (size_t)(n - 200) * 768);
            const float4 v = *(const float4*)(src + k0 + q * 4);
            half4 hv, lv;
            hv[0] = (_Float16)v.x; lv[0] = (_Float16)(v.x - (float)hv[0]);
            hv[1] = (_Float16)v.y; lv[1] = (_Float16)(v.y - (float)hv[1]);
            hv[2] = (_Float16)v.z; lv[2] = (_Float16)(v.z - (float)hv[2]);
            hv[3] = (_Float16)v.w; lv[3] = (_Float16)(v.w - (float)hv[3]);
            const int s    = (q >> 1) ^ (row & 7);
            const int addr = row * 64 + s * 8 + (q & 1) * 4;
            *(half4*)(Bh + addr) = hv;
            *(half4*)(Bl + addr) = lv;
        }
        __syncthreads();

        #pragma unroll
        for (int ks = 0; ks < 2; ++ks) {
            const int kslot = ks * 4 + grp;
            half8 ah[2], al[2], bh[5], bl[5];
            #pragma unroll
            for (int m = 0; m < 2; ++m) {
                const int row = w * 32 + m * 16 + r16;
                const int ad  = row * 64 + (kslot ^ (row & 7)) * 8;
                ah[m] = *(half8*)(Ah + ad);
                al[m] = *(half8*)(Al + ad);
            }
            #pragma unroll
            for (int n = 0; n < 5; ++n) {
                const int row = n * 16 + r16;
                const int ad  = row * 64 + (kslot ^ (row & 7)) * 8;
                bh[n] = *(half8*)(Bh + ad);
                bl[n] = *(half8*)(Bl + ad);
            }
            #pragma unroll
            for (int m = 0; m < 2; ++m)
                #pragma unroll
                for (int n = 0; n < 5; ++n) {
                    acc[m][n] = __builtin_amdgcn_mfma_f32_16x16x32_f16(ah[m], bh[n], acc[m][n], 0, 0, 0);
                    acc[m][n] = __builtin_amdgcn_mfma_f32_16x16x32_f16(ah[m], bl[n], acc[m][n], 0, 0, 0);
                    acc[m][n] = __builtin_amdgcn_mfma_f32_16x16x32_f16(al[m], bh[n], acc[m][n], 0, 0, 0);
                }
        }
    }

    #pragma unroll
    for (int m = 0; m < 2; ++m) {
        #pragma unroll
        for (int n = 0; n < 5; ++n) {
            #pragma unroll
            for (int i = 0; i < 4; ++i) {
                const size_t row = m0 + w * 32 + m * 16 + (lane >> 4) * 4 + i;
                const int    col = n0 + n * 16 + (lane & 15);
                xw[row * 400 + col] = acc[m][n][i];
            }
        }
    }
}

// ---------------------------------------------------------------------------
// Kernel 2: bidirectional LSTM recurrence. One block per (batch, dir).
// REVERTED to the Round-1 structure: best measured (457 us). All later
// "optimizations" (single barrier, shfl exchange, reg/LDS weight pinning)
// were neutral-to-worse: the kernel is serial-latency-bound with only 2
// independent chains per CU; per-step critical path is invariant.
// ---------------------------------------------------------------------------
__global__ __launch_bounds__(256) void k_lstm(
    const float* __restrict__ xw,     // [131072][400] (fwd gates 0..199, bwd 200..399)
    const float* __restrict__ Whh_f,  // [200][50]
    const float* __restrict__ Whh_b,
    const float* __restrict__ bf_,    // [200]
    const float* __restrict__ bb_,
    float* __restrict__ hout)         // [131072][100] (fwd 0..49, bwd 50..99)
{
    const int b   = blockIdx.x >> 1;
    const int dir = blockIdx.x & 1;
    const int g   = threadIdx.x;

    __shared__ float h_s[52];
    __shared__ float g_s[200];

    const float* Whh  = dir ? Whh_b : Whh_f;
    const float* bias = dir ? bb_ : bf_;

    float w[52];
    float bg = 0.f;
    if (g < 200) {
        #pragma unroll
        for (int j = 0; j < 50; ++j) w[j] = Whh[g * 50 + j];
        w[50] = 0.f; w[51] = 0.f;
        bg = bias[g];
    } else {
        #pragma unroll
        for (int j = 0; j < 52; ++j) w[j] = 0.f;
    }

    if (g < 52) h_s[g] = 0.f;
    float c = 0.f;
    __syncthreads();

    const size_t base = (size_t)b * 512;

    float xv = 0.f;
    {
        int t0 = dir ? 511 : 0;
        if (g < 200) xv = xw[(base + t0) * 400 + dir * 200 + g];
    }

    for (int it = 0; it < 512; ++it) {
        const int t = dir ? (511 - it) : it;
        float xcur = xv;
        if (it + 1 < 512) {
            int tn = dir ? (510 - it) : (it + 1);
            if (g < 200) xv = xw[(base + tn) * 400 + dir * 200 + g];
        }

        float sum = bg + xcur;
        const float4* h4 = (const float4*)h_s;
        #pragma unroll
        for (int q = 0; q < 13; ++q) {
            float4 hv = h4[q];
            sum = fmaf(w[q * 4 + 0], hv.x, sum);
            sum = fmaf(w[q * 4 + 1], hv.y, sum);
            sum = fmaf(w[q * 4 + 2], hv.z, sum);
            sum = fmaf(w[q * 4 + 3], hv.w, sum);
        }
        if (g < 200) g_s[g] = sum;
        __syncthreads();

        if (g < 50) {
            float gi = g_s[g];
            float gf = g_s[g + 50];
            float gg = g_s[g + 100];
            float go = g_s[g + 150];
            float si = 1.f / (1.f + expf(-gi));
            float sf = 1.f / (1.f + expf(-gf));
            float so = 1.f / (1.f + expf(-go));
            c = sf * c + si * tanhf(gg);
            float h = so * tanhf(c);
            hout[(base + t) * 100 + dir * 50 + g] = h;
            h_s[g] = h;
        }
        __syncthreads();
    }
}

// ---------------------------------------------------------------------------
// Kernel 3: emissions logits[bt][11] = hout[bt][100] @ Wout^T + bout
// ---------------------------------------------------------------------------
__global__ __launch_bounds__(256) void k_emis(
    const float* __restrict__ hout,   // [131072][100]
    const float* __restrict__ Wout,   // [11][100]
    const float* __restrict__ bout,   // [11]
    float* __restrict__ logits)       // [131072][11]
{
    __shared__ float Wl[1104];
    __shared__ float bl[11];
    const int tid = threadIdx.x;
    for (int i = tid; i < 1100; i += 256) Wl[i] = Wout[i];
    if (tid < 11) bl[tid] = bout[tid];
    __syncthreads();

    const size_t bt = (size_t)blockIdx.x * 256 + tid;
    const float4* h4 = (const float4*)(hout + bt * 100);
    float acc[11];
    #pragma unroll
    for (int k = 0; k < 11; ++k) acc[k] = bl[k];
    #pragma unroll
    for (int q = 0; q < 25; ++q) {
        float4 v = h4[q];
        #pragma unroll
        for (int k = 0; k < 11; ++k) {
            const float4 wv = *(const float4*)&Wl[k * 100 + q * 4];
            acc[k] = fmaf(v.x, wv.x, fmaf(v.y, wv.y, fmaf(v.z, wv.z, fmaf(v.w, wv.w, acc[k]))));
        }
    }
    #pragma unroll
    for (int k = 0; k < 11; ++k) logits[bt * 11 + k] = acc[k];
}

// ---------------------------------------------------------------------------
// Kernel 4: CRF forward scan + logsumexp score + fused Viterbi backtrace.
// LANE-PARALLEL exp: the 121 (prev,cur) pairs are spread over 64 lanes
// (2 items/lane) so each step computes at most 2 expf per lane instead of
// 11 expf on each of 11 lanes. Column max/argmax (first-max, ascending p)
// and the ORDERED p=0..10 sum run sequentially on thread c with the exact
// same values and order as before -> bitwise-identical alpha/score/paths.
// alpha and vmax broadcast via __shfl (no LDS round-trip). One wave, no
// barriers (same-wave LDS ops are ordered; lgkmcnt waits inserted).
// ---------------------------------------------------------------------------
__global__ __launch_bounds__(64, 1) void k_crf(
    const float* __restrict__ logits,   // [131072][11]
    const int* __restrict__ mask,       // [256][512]
    const float* __restrict__ trans,    // [11][11]
    float* __restrict__ scores,         // [256]
    float* __restrict__ paths)          // [256][512] (as float)
{
    const int b = blockIdx.x;
    const int lane = threadIdx.x;

    __shared__ float smat[11 * 12];     // [c][p], pad 12
    __shared__ float emat[11 * 12];
    __shared__ unsigned char bp[512][12];

    // item A: idx = lane (0..63); item B: idx = lane+64 (valid < 121)
    const int  pA = lane / 11, cA = lane - pA * 11;
    const bool hasB = (lane < 57);
    const int  iB = hasB ? (lane + 64) : 0;
    const int  pB = iB / 11, cB = iB - pB * 11;

    const float trA = trans[pA * 11 + cA];
    const float trB = hasB ? trans[pB * 11 + cB] : 0.f;

    float al_c = (lane == 9) ? 0.f : -1000.f;   // alpha[c] lives in lane c (<11)

    const size_t lbase = (size_t)b * 512;

    float fA = logits[lbase * 11 + cA];
    float fB = hasB ? logits[lbase * 11 + cB] : 0.f;
    int   m_cur = mask[lbase];

    for (int t = 0; t < 512; ++t) {
        float fA_n = 0.f, fB_n = 0.f; int m_n = 1;
        if (t + 1 < 512) {
            fA_n = logits[(lbase + t + 1) * 11 + cA];
            if (hasB) fB_n = logits[(lbase + t + 1) * 11 + cB];
            m_n = mask[lbase + t + 1];
        }

        const float alA = __shfl(al_c, pA);
        const float alB = __shfl(al_c, pB);
        const float vvA = (alA + fA) + trA;
        const float vvB = (alB + fB) + trB;
        smat[cA * 12 + pA] = vvA;
        if (hasB) smat[cB * 12 + pB] = vvB;

        // column max + argmax on thread c (first-max, ascending p: identical
        // to the sequential reference semantics)
        float vmax = -1e30f; int amax = 0;
        if (lane < 11) {
            float v[11];
            #pragma unroll
            for (int p = 0; p < 11; ++p) v[p] = smat[lane * 12 + p];
            #pragma unroll
            for (int p = 0; p < 11; ++p) {
                if (v[p] > vmax) { vmax = v[p]; amax = p; }
            }
        }
        const float vmA = __shfl(vmax, cA);
        const float vmB = __shfl(vmax, cB);

        // parallel exp (same inputs/values as the serial version)
        const float eA = expf(vvA - vmA);
        const float eB = expf(vvB - vmB);
        emat[cA * 12 + pA] = eA;
        if (hasB) emat[cB * 12 + pB] = eB;

        if (lane < 11) {
            float e[11];
            #pragma unroll
            for (int p = 0; p < 11; ++p) e[p] = emat[lane * 12 + p];
            float s = 0.f;
            #pragma unroll
            for (int p = 0; p < 11; ++p) s += e[p];   // ordered p=0..10
            const float na = vmax + logf(s);
            if (m_cur > 0) {
                al_c = na;
                bp[t][lane] = (unsigned char)amax;
            } else {
                bp[t][lane] = (unsigned char)lane;
            }
        }
        fA = fA_n; fB = fB_n; m_cur = m_n;
    }

    // final scores + argmax (STOP = 10)
    float fin = (lane < 11) ? (al_c + trans[lane * 11 + 10]) : -1e30f;
    float m = fin;
    int am = (lane < 11) ? lane : 1000;
    #pragma unroll
    for (int off = 8; off >= 1; off >>= 1) {
        float om = __shfl_xor(m, off, 16);
        int   oa = __shfl_xor(am, off, 16);
        if (om > m || (om == m && oa < am)) { m = om; am = oa; }
    }
    float s = (lane < 11) ? expf(fin - m) : 0.f;
    #pragma unroll
    for (int off = 8; off >= 1; off >>= 1) s += __shfl_xor(s, off, 16);

    if (lane == 0) {
        scores[b] = m + logf(s);
        int cur = am;
        paths[lbase + 511] = (float)cur;
        for (int t = 511; t >= 1; --t) {
            cur = bp[t][cur];
            paths[lbase + t - 1] = (float)cur;
        }
    }
}

// ---------------------------------------------------------------------------
extern "C" void kernel_launch(void* const* d_in, const int* in_sizes, int n_in,
                              void* d_out, int out_size, void* d_ws, size_t ws_size,
                              hipStream_t stream) {
    const float* emb   = (const float*)d_in[0];
    const int*   imask = (const int*)d_in[1];
    const float* Wihf  = (const float*)d_in[2];
    const float* Whhf  = (const float*)d_in[3];
    const float* bf_   = (const float*)d_in[4];
    const float* Wihb  = (const float*)d_in[5];
    const float* Whhb  = (const float*)d_in[6];
    const float* bb_   = (const float*)d_in[7];
    const float* Wout  = (const float*)d_in[8];
    const float* bout  = (const float*)d_in[9];
    const float* trans = (const float*)d_in[10];

    float* out = (float*)d_out;
    float* ws  = (float*)d_ws;
    float* xw     = ws;                          // 131072*400 f32 = 209.7 MB
    float* hout   = xw + (size_t)131072 * 400;   // 131072*100 f32 = 52.4 MB
    float* logits = hout + (size_t)131072 * 100; // 131072*11  f32 = 5.8 MB

    k_gemm_split<<<5120, 256, 0, stream>>>(emb, Wihf, Wihb, xw);
    k_lstm<<<512, 256, 0, stream>>>(xw, Whhf, Whhb, bf_, bb_, hout);
    k_emis<<<512, 256, 0, stream>>>(hout, Wout, bout, logits);
    k_crf<<<256, 64, 0, stream>>>(logits, imask, trans, out, out + 256);
}